// Round 1
// baseline (535.241 us; speedup 1.0000x reference)
//
#include <hip/hip_runtime.h>

#define H 128
#define MT 64
#define KB 16

// ---------------- GEMM: C[M x 128] = [A0 | A1] @ [[W0];[W1]] + b0 (+b1), opt relu
__global__ __launch_bounds__(256)
void k_gemm(const float* __restrict__ A0, int lda0,
            const float* __restrict__ A1, int lda1,
            int Ksplit, int K,
            const float* __restrict__ W0, const float* __restrict__ W1,
            const float* __restrict__ b0, const float* __restrict__ b1,
            float* __restrict__ C, int M, int do_relu)
{
    __shared__ float As[MT][KB + 1];   // +1 pad: avoid pow2-stride bank conflicts
    __shared__ float Bs[KB][H + 4];
    const int t = threadIdx.x;
    const int m0 = blockIdx.x * MT;
    const int tm4 = (t & 15) * 4;      // tm = lane&15 -> A reads 2-way (free), B reads broadcast
    const int tn8 = (t >> 4) * 8;
    float acc[4][8];
#pragma unroll
    for (int i = 0; i < 4; ++i)
#pragma unroll
        for (int j = 0; j < 8; ++j) acc[i][j] = 0.f;

    for (int k0 = 0; k0 < K; k0 += KB) {
        // A tile 64x16, k fastest for coalescing
#pragma unroll
        for (int j = 0; j < 4; ++j) {
            int idx = t + j * 256;
            int am = idx >> 4, ak = idx & 15;
            int gm = m0 + am, gk = k0 + ak;
            float v = 0.f;
            if (gm < M)
                v = (gk < Ksplit) ? A0[(size_t)gm * lda0 + gk]
                                  : A1[(size_t)gm * lda1 + (gk - Ksplit)];
            As[am][ak] = v;
        }
        // B tile 16x128, contiguous rows
#pragma unroll
        for (int j = 0; j < 8; ++j) {
            int idx = t + j * 256;
            int bk = idx >> 7, bc = idx & 127;
            int gk = k0 + bk;
            Bs[bk][bc] = (gk < Ksplit) ? W0[(size_t)gk * H + bc]
                                       : W1[(size_t)(gk - Ksplit) * H + bc];
        }
        __syncthreads();
#pragma unroll
        for (int kk = 0; kk < KB; ++kk) {
            float a[4], b[8];
#pragma unroll
            for (int i = 0; i < 4; ++i) a[i] = As[tm4 + i][kk];
#pragma unroll
            for (int j = 0; j < 8; ++j) b[j] = Bs[kk][tn8 + j];
#pragma unroll
            for (int i = 0; i < 4; ++i)
#pragma unroll
                for (int j = 0; j < 8; ++j) acc[i][j] += a[i] * b[j];
        }
        __syncthreads();
    }
#pragma unroll
    for (int i = 0; i < 4; ++i) {
        int gm = m0 + tm4 + i;
        if (gm < M) {
#pragma unroll
            for (int j = 0; j < 8; ++j) {
                int c = tn8 + j;
                float v = acc[i][j] + b0[c] + (b1 ? b1[c] : 0.f);
                if (do_relu) v = fmaxf(v, 0.f);
                C[(size_t)gm * H + c] = v;
            }
        }
    }
}

// ---------------- LayerNorm over H=128, optional relu+residual
__global__ __launch_bounds__(128)
void k_ln(const float* __restrict__ pre, const float* __restrict__ g,
          const float* __restrict__ be, const float* __restrict__ resid,
          float* __restrict__ out, int n)
{
    int node = blockIdx.x;
    int c = threadIdx.x;
    size_t idx = (size_t)node * H + c;
    float v = pre[idx];
    float s1 = v, s2 = v * v;
#pragma unroll
    for (int o = 32; o > 0; o >>= 1) {
        s1 += __shfl_xor(s1, o, 64);
        s2 += __shfl_xor(s2, o, 64);
    }
    __shared__ float r1[2], r2[2];
    int w = c >> 6, lane = c & 63;
    if (lane == 0) { r1[w] = s1; r2[w] = s2; }
    __syncthreads();
    float S1 = r1[0] + r1[1];
    float S2 = r2[0] + r2[1];
    float mu = S1 * (1.f / H);
    float var = S2 * (1.f / H) - mu * mu;
    float rs = rsqrtf(var + 1e-5f);
    float y = (v - mu) * rs * g[c] + be[c];
    if (resid) y = fmaxf(y, 0.f) + resid[idx];
    out[idx] = y;
}

// ---------------- CSR-based mean aggregation: agg[n] = mean over in-edges of h[src]
__global__ __launch_bounds__(128)
void k_aggregate(const float* __restrict__ h, const int* __restrict__ rp,
                 const int* __restrict__ col, float* __restrict__ agg, int n)
{
    int node = blockIdx.x;
    if (node >= n) return;
    int c = threadIdx.x;
    int beg = rp[node], end = rp[node + 1];
    float s = 0.f;
    int e = beg;
    for (; e + 4 <= end; e += 4) {
        int i0 = col[e], i1 = col[e + 1], i2 = col[e + 2], i3 = col[e + 3];
        s += h[(size_t)i0 * H + c] + h[(size_t)i1 * H + c] +
             h[(size_t)i2 * H + c] + h[(size_t)i3 * H + c];
    }
    for (; e < end; ++e) s += h[(size_t)col[e] * H + c];
    float d = (float)(end - beg);
    agg[(size_t)node * H + c] = s / fmaxf(d, 1.f);
}

// ---------------- CSR build helpers
__global__ void k_zero2(int* a, int* b, int n)
{
    int i = blockIdx.x * blockDim.x + threadIdx.x;
    if (i < n) { a[i] = 0; b[i] = 0; }
}

__global__ void k_count(const int* __restrict__ tgt, int* __restrict__ deg, int E)
{
    int i = blockIdx.x * blockDim.x + threadIdx.x;
    if (i < E) atomicAdd(&deg[tgt[i]], 1);
}

__global__ __launch_bounds__(1024)
void k_scan_block(const int* __restrict__ deg, int* __restrict__ incl,
                  int* __restrict__ bsum, int n)
{
    __shared__ int s[1024];
    int i = blockIdx.x * 1024 + threadIdx.x;
    int v = (i < n) ? deg[i] : 0;
    s[threadIdx.x] = v;
    __syncthreads();
    for (int off = 1; off < 1024; off <<= 1) {
        int t = (threadIdx.x >= off) ? s[threadIdx.x - off] : 0;
        __syncthreads();
        s[threadIdx.x] += t;
        __syncthreads();
    }
    if (i < n) incl[i] = s[threadIdx.x];
    if (threadIdx.x == 1023) bsum[blockIdx.x] = s[1023];
}

__global__ void k_scan_sums(int* bsum, int nb)
{
    if (threadIdx.x == 0 && blockIdx.x == 0) {
        int acc = 0;
        for (int b = 0; b < nb; ++b) { int v = bsum[b]; bsum[b] = acc; acc += v; }
    }
}

__global__ void k_scan_write(const int* __restrict__ incl, const int* __restrict__ boff,
                             int* __restrict__ rp, int n)
{
    int i = blockIdx.x * blockDim.x + threadIdx.x;
    if (i < n) {
        rp[i + 1] = incl[i] + boff[i >> 10];
        if (i == 0) rp[0] = 0;
    }
}

__global__ void k_fill(const int* __restrict__ srcs, const int* __restrict__ tgts,
                       const int* __restrict__ rp, int* __restrict__ fill,
                       int* __restrict__ col, int E)
{
    int i = blockIdx.x * blockDim.x + threadIdx.x;
    if (i < E) {
        int t = tgts[i];
        int p = atomicAdd(&fill[t], 1);
        col[rp[t] + p] = srcs[i];
    }
}

extern "C" void kernel_launch(void* const* d_in, const int* in_sizes, int n_in,
                              void* d_out, int out_size, void* d_ws, size_t ws_size,
                              hipStream_t stream)
{
    const float* x    = (const float*)d_in[0];
    const int*   ei   = (const int*)d_in[1];
    const float* w_in = (const float*)d_in[2];
    const float* b_in = (const float*)d_in[3];
    const float* ws0  = (const float*)d_in[4];
    const float* bs0  = (const float*)d_in[5];
    const float* wn0  = (const float*)d_in[6];
    const float* bn0  = (const float*)d_in[7];
    const float* g0   = (const float*)d_in[8];
    const float* be0  = (const float*)d_in[9];
    const float* ws1  = (const float*)d_in[10];
    const float* bs1  = (const float*)d_in[11];
    const float* wn1  = (const float*)d_in[12];
    const float* bn1  = (const float*)d_in[13];
    const float* g1   = (const float*)d_in[14];
    const float* be1  = (const float*)d_in[15];

    const int N = in_sizes[0] / 32;   // 50000
    const int E = in_sizes[1] / 2;    // 800000
    const int* srcs = ei;
    const int* tgts = ei + E;

    size_t NF = (size_t)N * H;
    float* hA  = (float*)d_ws;        // input-proj output / residual; later layer-1 pre-LN
    float* hB  = hA + NF;             // layer-0 pre-LN, then h1 (in-place LN)
    float* agg = hB + NF;
    int* deg  = (int*)(agg + NF);
    int* incl = deg + N;
    int* fill = incl + N;
    int* rp   = fill + N;
    int* bsum = rp + (N + 1);
    int* col  = bsum + 64;

    int gN = (N + 255) / 256;
    int gE = (E + 255) / 256;
    int gM = (N + MT - 1) / MT;
    int NB = (N + 1023) / 1024;

    // input projection + relu -> hA  (also residual for layer 0)
    k_gemm<<<gM, 256, 0, stream>>>(x, 32, nullptr, 0, 32, 32, w_in, nullptr,
                                   b_in, nullptr, hA, N, 1);
    // CSR build (once, reused by both layers)
    k_zero2<<<gN, 256, 0, stream>>>(deg, fill, N);
    k_count<<<gE, 256, 0, stream>>>(tgts, deg, E);
    k_scan_block<<<NB, 1024, 0, stream>>>(deg, incl, bsum, N);
    k_scan_sums<<<1, 64, 0, stream>>>(bsum, NB);
    k_scan_write<<<gN, 256, 0, stream>>>(incl, bsum, rp, N);
    k_fill<<<gE, 256, 0, stream>>>(srcs, tgts, rp, fill, col, E);

    // layer 0: gcn -> LN -> relu + residual
    k_aggregate<<<N, 128, 0, stream>>>(hA, rp, col, agg, N);
    k_gemm<<<gM, 256, 0, stream>>>(hA, H, agg, H, H, 2 * H, ws0, wn0, bs0, bn0,
                                   hB, N, 0);
    k_ln<<<N, 128, 0, stream>>>(hB, g0, be0, hA, hB, N);

    // layer 1: gcn -> LN -> d_out
    k_aggregate<<<N, 128, 0, stream>>>(hB, rp, col, agg, N);
    k_gemm<<<gM, 256, 0, stream>>>(hB, H, agg, H, H, 2 * H, ws1, wn1, bs1, bn1,
                                   hA, N, 0);
    k_ln<<<N, 128, 0, stream>>>(hA, g1, be1, nullptr, (float*)d_out, N);
}

// Round 2
// 383.121 us; speedup vs baseline: 1.3971x; 1.3971x over previous
//
#include <hip/hip_runtime.h>

#define H 128

typedef __bf16 bf16x8 __attribute__((ext_vector_type(8)));
typedef float f32x4 __attribute__((ext_vector_type(4)));

__device__ __forceinline__ float bf2f(unsigned short b) {
    return __uint_as_float(((unsigned int)b) << 16);
}
__device__ __forceinline__ unsigned short f2bf(float f) {
    unsigned int u = __float_as_uint(f);
    unsigned int r = (u + 0x7fffu + ((u >> 16) & 1u)) >> 16;   // RNE, finite values
    return (unsigned short)r;
}

// ---------- cast x (fp32) -> bf16, 4 elems/thread
__global__ __launch_bounds__(256)
void k_cast(const float* __restrict__ x, unsigned short* __restrict__ xb, int n4)
{
    int i = blockIdx.x * 256 + threadIdx.x;
    if (i < n4) {
        float4 v = ((const float4*)x)[i];
        unsigned short* o = xb + i * 4;
        o[0] = f2bf(v.x); o[1] = f2bf(v.y); o[2] = f2bf(v.z); o[3] = f2bf(v.w);
    }
}

// ---------- pack weights into MFMA B-fragment order + summed bias
// Wpack[((s*8+t)*64+l)*8 + j] = bf16( W[k = s*32 + (l>>4)*8 + j][c = t*16 + (l&15)] )
// where W row k: k<Ksplit -> W0[k][c], else W1[k-Ksplit][c]
__global__ __launch_bounds__(256)
void k_pack(const float* __restrict__ W0, const float* __restrict__ W1,
            const float* __restrict__ b0, const float* __restrict__ b1,
            unsigned short* __restrict__ Wpack, float* __restrict__ bsum,
            int Ksplit, int K)
{
    int idx = blockIdx.x * 256 + threadIdx.x;
    int total = K * 16;                 // (K/32)*8*64
    if (idx < total) {
        int l = idx & 63, tt = (idx >> 6) & 7, s = idx >> 9;
        int c = tt * 16 + (l & 15);
        int kb = s * 32 + ((l >> 4) & 3) * 8;
#pragma unroll
        for (int j = 0; j < 8; ++j) {
            int k = kb + j;
            float v = (k < Ksplit) ? W0[(size_t)k * H + c]
                                   : W1[(size_t)(k - Ksplit) * H + c];
            Wpack[(size_t)idx * 8 + j] = f2bf(v);
        }
    }
    if (idx < H) bsum[idx] = b0[idx] + (b1 ? b1[idx] : 0.f);
}

// ---------- MFMA GEMM: C[M x 128] = A[M x K](bf16) @ Wpack + bias
// block = 256 thr (4 waves), tile 128 rows; wave w -> rows w*32..w*32+31
template<int K, int RELU, int OUTBF>
__global__ __launch_bounds__(256)
void k_gemm_mfma(const unsigned short* __restrict__ A, int lda,
                 const unsigned short* __restrict__ Wpack,
                 const float* __restrict__ bias,
                 float* __restrict__ Cf, unsigned short* __restrict__ Cb,
                 int ldc, int M)
{
    constexpr int NS = K / 32;
    __shared__ unsigned short Bs[NS * 8 * 64 * 8];   // [s][nt][lane][j]
    const int t = threadIdx.x;
    {
        const uint4* wsrc = (const uint4*)Wpack;
        uint4* wdst = (uint4*)Bs;
        constexpr int CH = K * 16;                   // 16B chunks
#pragma unroll
        for (int i = t; i < CH; i += 256) wdst[i] = wsrc[i];
    }
    __syncthreads();

    const int wave = t >> 6, lane = t & 63;
    const int quad = lane >> 4, l16 = lane & 15;
    const int m0 = blockIdx.x * 128 + wave * 32;

    f32x4 acc[2][8];
#pragma unroll
    for (int mt = 0; mt < 2; ++mt)
#pragma unroll
        for (int nt = 0; nt < 8; ++nt) acc[mt][nt] = (f32x4){0.f, 0.f, 0.f, 0.f};

    // A fragments: all K upfront (independent dwordx4 loads, latency overlapped)
    bf16x8 afrag[NS][2];
#pragma unroll
    for (int s = 0; s < NS; ++s)
#pragma unroll
        for (int mt = 0; mt < 2; ++mt) {
            int row = m0 + mt * 16 + l16;
            if (row >= M) row = M - 1;
            afrag[s][mt] = *(const bf16x8*)(A + (size_t)row * lda + s * 32 + quad * 8);
        }

    const bf16x8* bfr = (const bf16x8*)Bs;
#pragma unroll
    for (int s = 0; s < NS; ++s)
#pragma unroll
        for (int nt = 0; nt < 8; ++nt) {
            bf16x8 b = bfr[(s * 8 + nt) * 64 + lane];
#pragma unroll
            for (int mt = 0; mt < 2; ++mt)
                acc[mt][nt] = __builtin_amdgcn_mfma_f32_16x16x32_bf16(
                    afrag[s][mt], b, acc[mt][nt], 0, 0, 0);
        }

#pragma unroll
    for (int nt = 0; nt < 8; ++nt) {
        float bv = bias[nt * 16 + l16];
        int col = nt * 16 + l16;
#pragma unroll
        for (int mt = 0; mt < 2; ++mt)
#pragma unroll
            for (int r = 0; r < 4; ++r) {
                int row = m0 + mt * 16 + quad * 4 + r;
                if (row < M) {
                    float v = acc[mt][nt][r] + bv;
                    if (RELU) v = fmaxf(v, 0.f);
                    if (OUTBF) Cb[(size_t)row * ldc + col] = f2bf(v);
                    else       Cf[(size_t)row * ldc + col] = v;
                }
            }
    }
}

// ---------- LayerNorm over H=128 (fp32 in), optional relu+residual(bf16), out bf16 or fp32
__global__ __launch_bounds__(128)
void k_ln(const float* __restrict__ pre, const float* __restrict__ g,
          const float* __restrict__ be, const unsigned short* __restrict__ resid,
          unsigned short* __restrict__ outb, float* __restrict__ outf,
          int ldo, int n)
{
    int node = blockIdx.x;
    int c = threadIdx.x;
    float v = pre[(size_t)node * H + c];
    float s1 = v, s2 = v * v;
#pragma unroll
    for (int o = 32; o > 0; o >>= 1) {
        s1 += __shfl_xor(s1, o, 64);
        s2 += __shfl_xor(s2, o, 64);
    }
    __shared__ float r1[2], r2[2];
    int w = c >> 6, lane = c & 63;
    if (lane == 0) { r1[w] = s1; r2[w] = s2; }
    __syncthreads();
    float S1 = r1[0] + r1[1];
    float S2 = r2[0] + r2[1];
    float mu = S1 * (1.f / H);
    float var = S2 * (1.f / H) - mu * mu;
    float rs = rsqrtf(var + 1e-5f);
    float y = (v - mu) * rs * g[c] + be[c];
    if (resid) y = fmaxf(y, 0.f) + bf2f(resid[(size_t)node * ldo + c]);
    if (outb) outb[(size_t)node * ldo + c] = f2bf(y);
    else      outf[(size_t)node * ldo + c] = y;
}

// ---------- CSR mean aggregation, bf16 in/out. One wave per node.
// h rows at stride 256 (cols 0..127); out at stride 256 (caller passes base+128).
__global__ __launch_bounds__(256)
void k_agg(const unsigned short* __restrict__ hb, const int* __restrict__ rp,
           const int* __restrict__ col, unsigned short* __restrict__ out, int n)
{
    int node = blockIdx.x * 4 + (threadIdx.x >> 6);
    if (node >= n) return;
    int lane = threadIdx.x & 63;
    int beg = rp[node], end = rp[node + 1];
    float s0 = 0.f, s1 = 0.f;
    int e = beg;
    for (; e + 2 <= end; e += 2) {
        int c0 = col[e], c1 = col[e + 1];
        unsigned int v0 = ((const unsigned int*)(hb + (size_t)c0 * 256))[lane];
        unsigned int v1 = ((const unsigned int*)(hb + (size_t)c1 * 256))[lane];
        s0 += bf2f((unsigned short)(v0 & 0xffff)) + bf2f((unsigned short)(v1 & 0xffff));
        s1 += bf2f((unsigned short)(v0 >> 16)) + bf2f((unsigned short)(v1 >> 16));
    }
    for (; e < end; ++e) {
        unsigned int v0 = ((const unsigned int*)(hb + (size_t)col[e] * 256))[lane];
        s0 += bf2f((unsigned short)(v0 & 0xffff));
        s1 += bf2f((unsigned short)(v0 >> 16));
    }
    float inv = 1.f / fmaxf((float)(end - beg), 1.f);
    unsigned int w = ((unsigned int)f2bf(s1 * inv) << 16) | f2bf(s0 * inv);
    ((unsigned int*)(out + (size_t)node * 256))[lane] = w;
}

// ---------------- CSR build helpers (unchanged from R1)
__global__ void k_zero2(int* a, int* b, int n)
{
    int i = blockIdx.x * blockDim.x + threadIdx.x;
    if (i < n) { a[i] = 0; b[i] = 0; }
}

__global__ void k_count(const int* __restrict__ tgt, int* __restrict__ deg, int E)
{
    int i = blockIdx.x * blockDim.x + threadIdx.x;
    if (i < E) atomicAdd(&deg[tgt[i]], 1);
}

__global__ __launch_bounds__(1024)
void k_scan_block(const int* __restrict__ deg, int* __restrict__ incl,
                  int* __restrict__ bsum, int n)
{
    __shared__ int s[1024];
    int i = blockIdx.x * 1024 + threadIdx.x;
    int v = (i < n) ? deg[i] : 0;
    s[threadIdx.x] = v;
    __syncthreads();
    for (int off = 1; off < 1024; off <<= 1) {
        int t = (threadIdx.x >= off) ? s[threadIdx.x - off] : 0;
        __syncthreads();
        s[threadIdx.x] += t;
        __syncthreads();
    }
    if (i < n) incl[i] = s[threadIdx.x];
    if (threadIdx.x == 1023) bsum[blockIdx.x] = s[1023];
}

__global__ void k_scan_sums(int* bsum, int nb)
{
    if (threadIdx.x == 0 && blockIdx.x == 0) {
        int acc = 0;
        for (int b = 0; b < nb; ++b) { int v = bsum[b]; bsum[b] = acc; acc += v; }
    }
}

__global__ void k_scan_write(const int* __restrict__ incl, const int* __restrict__ boff,
                             int* __restrict__ rp, int n)
{
    int i = blockIdx.x * blockDim.x + threadIdx.x;
    if (i < n) {
        rp[i + 1] = incl[i] + boff[i >> 10];
        if (i == 0) rp[0] = 0;
    }
}

__global__ void k_fill(const int* __restrict__ srcs, const int* __restrict__ tgts,
                       const int* __restrict__ rp, int* __restrict__ fill,
                       int* __restrict__ col, int E)
{
    int i = blockIdx.x * blockDim.x + threadIdx.x;
    if (i < E) {
        int t = tgts[i];
        int p = atomicAdd(&fill[t], 1);
        col[rp[t] + p] = srcs[i];
    }
}

extern "C" void kernel_launch(void* const* d_in, const int* in_sizes, int n_in,
                              void* d_out, int out_size, void* d_ws, size_t ws_size,
                              hipStream_t stream)
{
    const float* x    = (const float*)d_in[0];
    const int*   ei   = (const int*)d_in[1];
    const float* w_in = (const float*)d_in[2];
    const float* b_in = (const float*)d_in[3];
    const float* ws0  = (const float*)d_in[4];
    const float* bs0  = (const float*)d_in[5];
    const float* wn0  = (const float*)d_in[6];
    const float* bn0  = (const float*)d_in[7];
    const float* g0   = (const float*)d_in[8];
    const float* be0  = (const float*)d_in[9];
    const float* ws1  = (const float*)d_in[10];
    const float* bs1  = (const float*)d_in[11];
    const float* wn1  = (const float*)d_in[12];
    const float* bn1  = (const float*)d_in[13];
    const float* g1   = (const float*)d_in[14];
    const float* be1  = (const float*)d_in[15];

    const int N = in_sizes[0] / 32;   // 50000
    const int E = in_sizes[1] / 2;    // 800000
    const int* srcs = ei;
    const int* tgts = ei + E;

    // ---- workspace layout (bytes)
    char* w = (char*)d_ws;
    unsigned short* Acat0 = (unsigned short*)w;            w += (size_t)N * 256 * 2;
    unsigned short* Acat1 = (unsigned short*)w;            w += (size_t)N * 256 * 2;
    float*          pre   = (float*)w;                     w += (size_t)N * H * 4;
    unsigned short* x_bf  = (unsigned short*)w;            w += (size_t)N * 32 * 2;
    unsigned short* Wpin  = (unsigned short*)w;            w += 32 * H * 2;
    unsigned short* Wp0   = (unsigned short*)w;            w += 256 * H * 2;
    unsigned short* Wp1   = (unsigned short*)w;            w += 256 * H * 2;
    float* bin  = (float*)w;                               w += H * 4;
    float* bsm0 = (float*)w;                               w += H * 4;
    float* bsm1 = (float*)w;                               w += H * 4;
    int* deg  = (int*)w;                                   w += (size_t)N * 4;
    int* incl = (int*)w;                                   w += (size_t)N * 4;
    int* fill = (int*)w;                                   w += (size_t)N * 4;
    int* rp   = (int*)w;                                   w += (size_t)(N + 1) * 4;
    int* bsum = (int*)w;                                   w += 64 * 4;
    int* col  = (int*)w;

    int gN = (N + 255) / 256;
    int gE = (E + 255) / 256;
    int gM = (N + 127) / 128;
    int NB = (N + 1023) / 1024;

    // prep: casts + weight packing (tiny)
    k_cast<<<(N * 32 / 4 + 255) / 256, 256, 0, stream>>>(x, x_bf, N * 32 / 4);
    k_pack<<<2, 256, 0, stream>>>(w_in, nullptr, b_in, nullptr, Wpin, bin, 32, 32);
    k_pack<<<16, 256, 0, stream>>>(ws0, wn0, bs0, bn0, Wp0, bsm0, 128, 256);
    k_pack<<<16, 256, 0, stream>>>(ws1, wn1, bs1, bn1, Wp1, bsm1, 128, 256);

    // CSR build (once, reused by both layers)
    k_zero2<<<gN, 256, 0, stream>>>(deg, fill, N);
    k_count<<<gE, 256, 0, stream>>>(tgts, deg, E);
    k_scan_block<<<NB, 1024, 0, stream>>>(deg, incl, bsum, N);
    k_scan_sums<<<1, 64, 0, stream>>>(bsum, NB);
    k_scan_write<<<gN, 256, 0, stream>>>(incl, bsum, rp, N);
    k_fill<<<gE, 256, 0, stream>>>(srcs, tgts, rp, fill, col, E);

    // input projection + relu -> Acat0[:, 0:128] (bf16)
    k_gemm_mfma<32, 1, 1><<<gM, 256, 0, stream>>>(x_bf, 32, Wpin, bin,
                                                  nullptr, Acat0, 256, N);

    // layer 0
    k_agg<<<(N + 3) / 4, 256, 0, stream>>>(Acat0, rp, col, Acat0 + 128, N);
    k_gemm_mfma<256, 0, 0><<<gM, 256, 0, stream>>>(Acat0, 256, Wp0, bsm0,
                                                   pre, nullptr, H, N);
    k_ln<<<N, 128, 0, stream>>>(pre, g0, be0, Acat0, Acat1, nullptr, 256, N);

    // layer 1
    k_agg<<<(N + 3) / 4, 256, 0, stream>>>(Acat1, rp, col, Acat1 + 128, N);
    k_gemm_mfma<256, 0, 0><<<gM, 256, 0, stream>>>(Acat1, 256, Wp1, bsm1,
                                                   pre, nullptr, H, N);
    k_ln<<<N, 128, 0, stream>>>(pre, g1, be1, nullptr, nullptr, (float*)d_out, H, N);
}